// Round 10
// baseline (1364.461 us; speedup 1.0000x reference)
//
#include <hip/hip_runtime.h>

// DHPM fused forward v10 (MI355X / gfx950).
// Register-budget-driven redesign. gfx950's unified VGPR/AGPR file means the
// occupancy budget is arch+acc TOTAL; demand must sit well under 128 for
// 4 waves/SIMD. So: 6 channels split THREE ways -> aP[2][7] = 56 VGPR.
// Block = 384 thr = 6 waves = 2 pt-halves x 3 channel-pair groups:
//   g0: {Y0,  Ydx}  -> sincos -> wc,wsn; val, dx, xxA(-wsn*Ydx^2); sends wc,wsn
//   g1: {Yxx, Ydy}  -> xxB(+wc*Yxx), dy, yyA(-wsn*Ydy^2)
//   g2: {Yyy, Ydt}  -> yyB(+wc*Yyy), dt
// xx = xxA+xxB, yy = yyA+yyB summed in a tiny fixup pass. One barrier per
// nt (parity-double-buffered exchange). No launch_bounds cap -> no spill.

#define HID 200
#define NT 13
#define KT 7
#define BLDK 232           // f16 row stride of W tiles (464 B = 29 granules, odd)
#define WCHUNK 8192
#define NTH 384
#define RLD 36             // res/exchange row stride (floats; 9 granules, odd)

#define OFF_WU 0           // [13][16][232] f16, 8 KB padded per nt
#define OFF_WV 106496
#define OFF_WF 212992
#define OFF_CU 319488      // [200][8] f32 {ax,ay,at,b0,-ax^2,-ay^2,0,0}
#define OFF_CV 325888
#define OFF_CF 332288      // [200][16] f32 {Wf0 row(12), bf0, pad}

typedef _Float16 f16;
typedef _Float16 f16x2 __attribute__((ext_vector_type(2)));
typedef _Float16 f16x8 __attribute__((ext_vector_type(8)));
typedef float f32x4 __attribute__((ext_vector_type(4)));

#define GLDS16(gp, lp) __builtin_amdgcn_global_load_lds( \
    (const __attribute__((address_space(1))) void*)(gp), \
    (__attribute__((address_space(3))) void*)(lp), 16, 0, 0)

__global__ __launch_bounds__(256) void dhpm_prep(
    const float* __restrict__ Wu1, const float* __restrict__ Wv1, const float* __restrict__ Wf1,
    const float* __restrict__ Wu0, const float* __restrict__ bu0,
    const float* __restrict__ Wv0, const float* __restrict__ bv0,
    const float* __restrict__ Wf0, const float* __restrict__ bf0,
    char* __restrict__ ws)
{
    int id = blockIdx.x * blockDim.x + threadIdx.x;
    const int nW = 3 * NT * 16 * 116;   // 72384
    if (id < nW) {
        const int net = id / (NT*16*116);
        int e = id - net * (NT*16*116);
        const int nt  = e / (16*116);  e -= nt * (16*116);
        const int row = e / 116;
        const int k2  = e - row * 116;
        const int j   = nt*16 + row;
        const int k   = k2*2;
        const float* W = (net == 0) ? Wu1 : (net == 1) ? Wv1 : Wf1;
        f16x2 v; v[0] = (f16)0.f; v[1] = (f16)0.f;
        if (j < HID) {
            if (k     < HID) v[0] = (f16)W[j*HID + k];
            if (k + 1 < HID) v[1] = (f16)W[j*HID + k + 1];
        }
        *(f16x2*)(ws + net*106496 + nt*WCHUNK + row*464 + k2*4) = v;
        return;
    }
    id -= nW;
    if (id < 400) {
        const int net = id / HID;
        const int r   = id - net*HID;
        const float* W0 = net ? Wv0 : Wu0;
        const float* b0 = net ? bv0 : bu0;
        const float ax = W0[r*3+0], ay = W0[r*3+1], at = W0[r*3+2];
        float4 c0, c1;
        c0.x = ax; c0.y = ay; c0.z = at; c0.w = b0[r];
        c1.x = -ax*ax; c1.y = -ay*ay; c1.z = 0.f; c1.w = 0.f;
        char* p = ws + (net ? OFF_CV : OFF_CU) + r*32;
        *(float4*)(p)      = c0;
        *(float4*)(p + 16) = c1;
        return;
    }
    id -= 400;
    if (id < HID) {
        const int i = id;
        float4 c0, c1, c2, c3;
        c0.x = Wf0[i*12+0];  c0.y = Wf0[i*12+1];  c0.z = Wf0[i*12+2];  c0.w = Wf0[i*12+3];
        c1.x = Wf0[i*12+4];  c1.y = Wf0[i*12+5];  c1.z = Wf0[i*12+6];  c1.w = Wf0[i*12+7];
        c2.x = Wf0[i*12+8];  c2.y = Wf0[i*12+9];  c2.z = Wf0[i*12+10]; c2.w = Wf0[i*12+11];
        c3.x = bf0[i]; c3.y = 0.f; c3.z = 0.f; c3.w = 0.f;
        char* p = ws + OFF_CF + i*64;
        *(float4*)(p)      = c0;
        *(float4*)(p + 16) = c1;
        *(float4*)(p + 32) = c2;
        *(float4*)(p + 48) = c3;
    }
}

__device__ __forceinline__ f32x4 mfma16(f16x8 a, f16x8 b, f32x4 c) {
    return __builtin_amdgcn_mfma_f32_16x16x32_f16(a, b, c, 0, 0, 0);
}

__device__ __forceinline__ void run_net(
    const float* __restrict__ inp, const char* __restrict__ ws,
    const int wOff, const int cstOff,
    const float* __restrict__ b1, const float* __restrict__ W2, const float b2s,
    const int cV, const int cDX, const int cXX, const int cDY,
    const int cYY, const int cDT, const int sXX, const int sYY,
    char* __restrict__ Bb0, char* __restrict__ Bb1,
    float* __restrict__ exch, float* __restrict__ res,
    const int gp0, const int t, const int lane, const int w,
    const int h, const int g, const int jl, const int klo)
{
    const char* src = ws + wOff;

    // stage nt=0 -> Bb0 (464 x 16B chunks over 384 thr), overlaps A'-build
    for (int c = t; c < 464; c += NTH)
        GLDS16(src + c*16, Bb0 + c*16);

    // ---- A' fragments: 2 channels x 7 kt = 56 VGPR ----
    f16x8 aP[2][KT];
    {
        const float4* cst = (const float4*)(ws + cstOff);   // [200][2] float4
        const int pt = gp0 + h*16 + jl;
        const float x = inp[pt*3+0], y = inp[pt*3+1], tt = inp[pt*3+2];
        #pragma unroll
        for (int kt = 0; kt < KT; ++kt) {
            f16x8 f0, f1;
            #pragma unroll
            for (int e = 0; e < 8; ++e) {
                const int i = kt*32 + klo*8 + e;
                const int ic = (i < HID) ? i : 0;   // pad-k cols of B are 0
                const float4 c = cst[ic*2];
                const float4 c2 = cst[ic*2+1];      // {-ax^2, -ay^2, -, -}
                const float z = fmaf(c.x, x, fmaf(c.y, y, fmaf(c.z, tt, c.w)));
                float s, cv;
                __sincosf(z, &s, &cv);
                if (g == 0)      { f0[e] = (f16)s;          f1[e] = (f16)(cv*c.x); }
                else if (g == 1) { f0[e] = (f16)(s * c2.x); f1[e] = (f16)(cv*c.y); }
                else             { f0[e] = (f16)(s * c2.y); f1[e] = (f16)(cv*c.z); }
            }
            aP[0][kt] = f0; aP[1][kt] = f1;
        }
    }

    float pA[4] = {0,0,0,0}, pB[4] = {0,0,0,0}, pC[4] = {0,0,0,0};

    __syncthreads();   // Bb0 landed (vmcnt drain); prior-phase LDS dead

    for (int nt = 0; nt < NT; ++nt) {
        const char* Bcur = (nt & 1) ? Bb1 : Bb0;
        char*       Bnxt = (nt & 1) ? Bb0 : Bb1;
        if (nt + 1 < NT) {
            const char* s2 = src + (nt+1)*WCHUNK;
            for (int c = t; c < 464; c += NTH)
                GLDS16(s2 + c*16, Bnxt + c*16);
        }

        const int j = nt*16 + jl;
        float bj = 0.f, wj = 0.f;
        if (g == 0 && j < HID) { bj = b1[j]; wj = W2[j]; }

        f32x4 acc0 = {0,0,0,0}, acc1 = {0,0,0,0};
        const f16* BH = (const f16*)Bcur;
        #pragma unroll
        for (int kt = 0; kt < KT; ++kt) {
            const f16x8 b = *(const f16x8*)&BH[jl*BLDK + kt*32 + klo*8];
            acc0 = mfma16(aP[0][kt], b, acc0);
            acc1 = mfma16(aP[1][kt], b, acc1);
        }

        const int pcol = h*16 + klo*4;
        float* EX = exch + (nt & 1) * (2*16*RLD);
        f32x4 ws4;
        if (g == 0) {
            f32x4 wc4;
            #pragma unroll
            for (int r = 0; r < 4; ++r) {
                float s1, c1;
                __sincosf(acc0[r] + bj, &s1, &c1);
                wc4[r] = wj * c1;
                ws4[r] = wj * s1;
                pA[r] += ws4[r];                                    // val
                pB[r] = fmaf(wc4[r], acc1[r], pB[r]);               // dx
                pC[r] = fmaf(-ws4[r]*acc1[r], acc1[r], pC[r]);      // xxA
            }
            *(f32x4*)&EX[jl*RLD + pcol] = wc4;
            *(f32x4*)&EX[16*RLD + jl*RLD + pcol] = ws4;
        }
        __syncthreads();   // exch visible; Bnxt landed; Bcur reads done
        if (g == 1) {
            const f32x4 wc4 = *(const f32x4*)&EX[jl*RLD + pcol];
            const f32x4 wv4 = *(const f32x4*)&EX[16*RLD + jl*RLD + pcol];
            #pragma unroll
            for (int r = 0; r < 4; ++r) {
                pA[r] = fmaf(wc4[r], acc0[r], pA[r]);               // xxB
                pB[r] = fmaf(wc4[r], acc1[r], pB[r]);               // dy
                pC[r] = fmaf(-wv4[r]*acc1[r], acc1[r], pC[r]);      // yyA
            }
        } else if (g == 2) {
            const f32x4 wc4 = *(const f32x4*)&EX[jl*RLD + pcol];
            #pragma unroll
            for (int r = 0; r < 4; ++r) {
                pA[r] = fmaf(wc4[r], acc0[r], pA[r]);               // yyB
                pB[r] = fmaf(wc4[r], acc1[r], pB[r]);               // dt
            }
        }
    }

    // butterfly over the 16 j-lanes
    #pragma unroll
    for (int d = 1; d < 16; d <<= 1)
        #pragma unroll
        for (int r = 0; r < 4; ++r) {
            pA[r] += __shfl_xor(pA[r], d);
            pB[r] += __shfl_xor(pB[r], d);
            pC[r] += __shfl_xor(pC[r], d);
        }
    if (jl == 0) {
        const int p0 = h*16 + klo*4;
        f32x4 vA, vB, vC;
        #pragma unroll
        for (int r = 0; r < 4; ++r) {
            vA[r] = pA[r] + ((g == 0) ? b2s : 0.f);
            vB[r] = pB[r];
            vC[r] = pC[r];
        }
        const int cA = (g == 0) ? cV  : (g == 1) ? cXX : cYY;
        const int cB = (g == 0) ? cDX : (g == 1) ? cDY : cDT;
        *(f32x4*)&res[cA*RLD + p0] = vA;
        *(f32x4*)&res[cB*RLD + p0] = vB;
        if (g == 0) *(f32x4*)&res[sXX*RLD + p0] = vC;
        if (g == 1) *(f32x4*)&res[sYY*RLD + p0] = vC;
    }
}

__global__ __launch_bounds__(NTH) void dhpm_main(
    const float* __restrict__ inp, const char* __restrict__ ws,
    const float* __restrict__ bu1, const float* __restrict__ Wu2, const float* __restrict__ bu2,
    const float* __restrict__ bv1, const float* __restrict__ Wv2, const float* __restrict__ bv2,
    const float* __restrict__ bf1, const float* __restrict__ Wf2, const float* __restrict__ bf2,
    float* __restrict__ out, const int Np)
{
    __shared__ __align__(16) char LDS[29728];
    char*  Bb0  = LDS;                        // 8 KB
    char*  Bb1  = LDS + 8192;                 // 8 KB
    float* exch = (float*)(LDS + 16384);      // 2 par x 2 arr x 16 x 36 x4 = 9216 B
    f16*   Af   = (f16*)LDS;                  // f-net: [32][232] f16 = 14848 B (aliases)
    float* res  = (float*)(LDS + 25600);      // [18][36] f32 = 2592 B
    float* pfb  = (float*)(LDS + 28192);      // [6][2][32] f32 = 1536 B

    const int t = threadIdx.x;
    const int lane = t & 63;
    const int w = __builtin_amdgcn_readfirstlane(t >> 6);   // 0..5
    const int h = w & 1, g = w >> 1;
    const int jl = lane & 15, klo = lane >> 4;
    const int gp0 = blockIdx.x * 32;

    run_net(inp, ws, OFF_WU, OFF_CU, bu1, Wu2, bu2[0],
            0, 4, 5, 6, 7, 2, 14, 15,
            Bb0, Bb1, exch, res, gp0, t, lane, w, h, g, jl, klo);
    run_net(inp, ws, OFF_WV, OFF_CV, bv1, Wv2, bv2[0],
            1, 8, 9, 10, 11, 3, 16, 17,
            Bb0, Bb1, exch, res, gp0, t, lane, w, h, g, jl, klo);

    __syncthreads();   // all res partial cols written
    if (t < 32) {      // xx/yy pair-sum fixup
        res[5*RLD  + t] += res[14*RLD + t];
        res[7*RLD  + t] += res[15*RLD + t];
        res[9*RLD  + t] += res[16*RLD + t];
        res[11*RLD + t] += res[17*RLD + t];
    }
    __syncthreads();   // res cols 0..11 final; Bb/exch region free

    // ======================= f-net =======================
    if (w < 2) {   // waves 0,1 build A_f for pts w*16+jl
        const int p = w*16 + jl;
        float fv[12];
        #pragma unroll
        for (int k = 0; k < 12; ++k) fv[k] = res[k*RLD + p];
        const float4* cf = (const float4*)(ws + OFF_CF);
        #pragma unroll
        for (int kt = 0; kt < KT; ++kt) {
            f16x8 f;
            #pragma unroll
            for (int e = 0; e < 8; ++e) {
                const int i = kt*32 + klo*8 + e;
                const int ic = (i < HID) ? i : 0;
                const float4 c0 = cf[ic*4+0];
                const float4 c1 = cf[ic*4+1];
                const float4 c2 = cf[ic*4+2];
                const float4 c3 = cf[ic*4+3];
                float z = c3.x;
                z = fmaf(c0.x, fv[0], z);  z = fmaf(c0.y, fv[1], z);
                z = fmaf(c0.z, fv[2], z);  z = fmaf(c0.w, fv[3], z);
                z = fmaf(c1.x, fv[4], z);  z = fmaf(c1.y, fv[5], z);
                z = fmaf(c1.z, fv[6], z);  z = fmaf(c1.w, fv[7], z);
                z = fmaf(c2.x, fv[8], z);  z = fmaf(c2.y, fv[9], z);
                z = fmaf(c2.z, fv[10], z); z = fmaf(c2.w, fv[11], z);
                f[e] = (f16)__sinf(z);
            }
            *(f16x8*)((char*)Af + p*464 + kt*64 + klo*16) = f;
        }
    }
    __syncthreads();   // A_f complete

    float pf0[2][4] = {{0,0,0,0},{0,0,0,0}};
    float pf1[2][4] = {{0,0,0,0},{0,0,0,0}};
    for (int rd = 0; rd < 3; ++rd) {
        const int nt = w + rd*6;
        if (nt >= NT) break;   // wave-uniform
        f16x8 bF[KT];
        #pragma unroll
        for (int kt = 0; kt < KT; ++kt)
            bF[kt] = *(const f16x8*)(ws + OFF_WF + nt*WCHUNK
                                      + jl*464 + kt*64 + klo*16);
        f32x4 accF[2] = {{0,0,0,0},{0,0,0,0}};
        #pragma unroll
        for (int kt = 0; kt < KT; ++kt) {
            const f16x8 a0 = *(const f16x8*)((const char*)Af + jl*464 + kt*64 + klo*16);
            const f16x8 a1 = *(const f16x8*)((const char*)Af + (16+jl)*464 + kt*64 + klo*16);
            accF[0] = mfma16(a0, bF[kt], accF[0]);
            accF[1] = mfma16(a1, bF[kt], accF[1]);
        }
        const int j = nt*16 + jl;
        const float bj = (j < HID) ? bf1[j] : 0.f;
        const float wa = (j < HID) ? Wf2[j] : 0.f;
        const float wb = (j < HID) ? Wf2[HID + j] : 0.f;
        #pragma unroll
        for (int mt = 0; mt < 2; ++mt)
            #pragma unroll
            for (int r = 0; r < 4; ++r) {
                const float hh = __sinf(accF[mt][r] + bj);
                pf0[mt][r] = fmaf(wa, hh, pf0[mt][r]);
                pf1[mt][r] = fmaf(wb, hh, pf1[mt][r]);
            }
    }

    #pragma unroll
    for (int d = 1; d < 16; d <<= 1)
        #pragma unroll
        for (int mt = 0; mt < 2; ++mt)
            #pragma unroll
            for (int r = 0; r < 4; ++r) {
                pf0[mt][r] += __shfl_xor(pf0[mt][r], d);
                pf1[mt][r] += __shfl_xor(pf1[mt][r], d);
            }
    if (jl == 0) {
        #pragma unroll
        for (int mt = 0; mt < 2; ++mt) {
            const int p0 = mt*16 + klo*4;
            f32x4 v0, v1;
            #pragma unroll
            for (int r = 0; r < 4; ++r) { v0[r] = pf0[mt][r]; v1[r] = pf1[mt][r]; }
            *(f32x4*)&pfb[w*64 + 0*32 + p0] = v0;
            *(f32x4*)&pfb[w*64 + 1*32 + p0] = v1;
        }
    }
    __syncthreads();
    if (t < 64) {
        const int pt = t & 31, ch = t >> 5;
        float s = bf2[ch];
        #pragma unroll
        for (int ww = 0; ww < 6; ++ww) s += pfb[ww*64 + ch*32 + pt];
        res[(12 + ch)*RLD + pt] = s;
    }
    __syncthreads();

    // coalesced final store
    for (int e = t; e < 14*32; e += NTH) {
        const int c = e >> 5, p = e & 31;
        out[(size_t)c*Np + gp0 + p] = res[c*RLD + p];
    }
}

extern "C" void kernel_launch(void* const* d_in, const int* in_sizes, int n_in,
                              void* d_out, int out_size, void* d_ws, size_t ws_size,
                              hipStream_t stream) {
    const float* inp = (const float*)d_in[0];
    const float* Wu0 = (const float*)d_in[1];  const float* bu0 = (const float*)d_in[2];
    const float* Wu1 = (const float*)d_in[3];  const float* bu1 = (const float*)d_in[4];
    const float* Wu2 = (const float*)d_in[5];  const float* bu2 = (const float*)d_in[6];
    const float* Wv0 = (const float*)d_in[7];  const float* bv0 = (const float*)d_in[8];
    const float* Wv1 = (const float*)d_in[9];  const float* bv1 = (const float*)d_in[10];
    const float* Wv2 = (const float*)d_in[11]; const float* bv2 = (const float*)d_in[12];
    const float* Wf0 = (const float*)d_in[13]; const float* bf0 = (const float*)d_in[14];
    const float* Wf1 = (const float*)d_in[15]; const float* bf1 = (const float*)d_in[16];
    const float* Wf2 = (const float*)d_in[17]; const float* bf2 = (const float*)d_in[18];
    float* out = (float*)d_out;
    char* ws = (char*)d_ws;   // ~345 KB used

    const int Np = in_sizes[0] / 3;  // 262144

    const int nTot = 3*NT*16*116 + 400 + HID;  // 72984
    dhpm_prep<<<(nTot + 255) / 256, 256, 0, stream>>>(
        Wu1, Wv1, Wf1, Wu0, bu0, Wv0, bv0, Wf0, bf0, ws);
    dhpm_main<<<Np / 32, NTH, 0, stream>>>(
        inp, ws, bu1, Wu2, bu2, bv1, Wv2, bv2, bf1, Wf2, bf2, out, Np);
}